// Round 9
// baseline (215.802 us; speedup 1.0000x reference)
//
#include <hip/hip_runtime.h>
#include <hip/hip_bf16.h>
#include <math.h>

// PairwiseCosineSimilarity: C[n][m] = <x1[n],x2[m]> / (max(||x1||,eps)*max(||x2||,eps))
// Round 9: normalize rows -> bf16, then PERSISTENT 256x256-tile MFMA GEMM:
//   - 256 blocks (1/CU), each computes 4 consecutive column-tiles of one row.
//   - ONE seamless 64-K-tile pipeline per block (r5's verified 4-phase schedule,
//     counted vmcnt, never drains); staging for K-tile g+1 crosses output-tile
//     boundaries (B panel pointer switches; A panel L1/L2-reused 4x).
//   - inline epilogue at tile boundaries: bar -> vmcnt(4) -> fire-and-forget
//     128 C-stores + acc reset -> MFMA. Stores retire under ph4's vmcnt(2)
//     ~3 phases later (no wait counts past 63; queue math in comments).
// Zero-conflict XOR-swizzled LDS (pre-swizzled global source + swizzled read),
// setprio around MFMA, XCD-aware bijective block swizzle, alignas(16) LDS.

typedef __bf16 bf16x8 __attribute__((ext_vector_type(8)));
typedef float  f32x4  __attribute__((ext_vector_type(4)));

#define LDSP(x) ((__attribute__((address_space(3))) void*)(x))
#define GLBP(x) ((const __attribute__((address_space(1))) void*)(x))

#define BM 256
#define BN 256
#define BK 64
#define TPB 4          // output tiles per persistent block
#define EPS_CS 1e-8f

// ---------------- normalize: one block per row, D == 1024 ----------------

__global__ __launch_bounds__(256) void nrm_bf16_1024(const float* __restrict__ in,
                                                     __bf16* __restrict__ out) {
    const int row = blockIdx.x;
    const int t = threadIdx.x;
    const float4 v = reinterpret_cast<const float4*>(in + (size_t)row * 1024)[t];
    float ss = v.x * v.x + v.y * v.y + v.z * v.z + v.w * v.w;
#pragma unroll
    for (int off = 32; off > 0; off >>= 1) ss += __shfl_down(ss, off, 64);
    __shared__ float red[4];
    const int lane = t & 63, wid = t >> 6;
    if (lane == 0) red[wid] = ss;
    __syncthreads();
    const float tot = red[0] + red[1] + red[2] + red[3];
    const float rn = 1.0f / fmaxf(sqrtf(tot), EPS_CS);
    ushort4 pk;
    pk.x = __builtin_bit_cast(unsigned short, (__bf16)(v.x * rn));
    pk.y = __builtin_bit_cast(unsigned short, (__bf16)(v.y * rn));
    pk.z = __builtin_bit_cast(unsigned short, (__bf16)(v.z * rn));
    pk.w = __builtin_bit_cast(unsigned short, (__bf16)(v.w * rn));
    reinterpret_cast<ushort4*>(out + (size_t)row * 1024)[t] = pk;
}

// ------------- persistent 256x256 pipelined MFMA GEMM: C = A * B^T -------------
// A[NR][D], B[NC][D] bf16 row-major; C[NR][NC] f32. D == 1024 (16 K-tiles/tile).
// Grid = tiles/TPB blocks (1/CU), block = 512 (8 waves, 2x4). Per wave: 128x64
// output, acc[8][4] f32x4. LDS: 2 x (A 256x64 + B 256x64) bf16 = 128 KB.
//
// Per-K-tile schedule (r5, verified): 4 phases x {reads | stage | bar | MFMA | bar},
// stages: ph1 -> B0-3(g+1), ph2 -> A0,A2,A1,A3(g+1); waits: vmcnt(4) in ph1
// (retires A1,A3 of g; 3-phase flight), vmcnt(2) end of ph4 (retires B0-3,A0,A2
// of g+1; 2-3 phase flight). Queue floor = 2; never drains.
// Tile boundary (g%16==0, g>0): ph1 becomes reads|stageB|bar|vmcnt(4)|
// 128 C-stores + acc reset|MFMA|bar. Stores enter the queue after B0-3(g+1) and
// before A*(g+1); ph4's vmcnt(2) retires [B0-3, stores, A0, A2] keeping [A1,A3].

__global__ __launch_bounds__(512, 1) void gemm_nt_bf16_persist(const __bf16* __restrict__ A,
                                                               const __bf16* __restrict__ B,
                                                               float* __restrict__ C,
                                                               int NC, int D) {
    __shared__ alignas(16) __bf16 As[2][BM * BK];   // 2 x 32 KB
    __shared__ alignas(16) __bf16 Bs[2][BN * BK];   // 2 x 32 KB

    const int t    = threadIdx.x;
    const int lane = t & 63;
    const int wid  = t >> 6;            // 0..7
    const int wm   = wid >> 2;          // 0..1  (128-row strip)
    const int wn   = wid & 3;           // 0..3  (64-col strip)
    const int fr   = lane & 15;         // fragment row/col
    const int fq   = lane >> 4;         // 0..3  (k sub-group)
    const int xk   = fr & 7;            // read XOR key == (row & 7)
    const int g0   = fq ^ xk;           // kh=0 physical 16B-group
    const int g1   = (4 + fq) ^ xk;     // kh=1 physical 16B-group

    // XCD-aware bijective block swizzle (grid % 8 == 0 on the fast path)
    const int nwg = gridDim.x;
    int b = blockIdx.x;
    if ((nwg & 7) == 0) b = (b & 7) * (nwg >> 3) + (b >> 3);
    const int ntn   = NC / BN;
    const int tile0 = b * TPB;           // 4 consecutive tiles, same row (ntn%4==0)
    const int trow  = tile0 / ntn;
    const int tcol0 = tile0 % ntn;
    const int brow  = trow * BM;

    // staging: thread t covers LDS elements [t*8, t*8+8) of a 64-row slab.
    // source k-group pre-swizzled: (t&7) ^ (row&7) (inverse of the read XOR).
    const int srow = t >> 3;                         // 0..63
    const int sg8  = ((t & 7) ^ (srow & 7)) << 3;
    const __bf16* aSrc = A + (size_t)(brow + srow) * D + sg8;   // A panel: whole block
    const __bf16* bP0 = B + (size_t)((tcol0 + 0) * BN + srow) * D + sg8;
    const __bf16* bP1 = B + (size_t)((tcol0 + 1) * BN + srow) * D + sg8;
    const __bf16* bP2 = B + (size_t)((tcol0 + 2) * BN + srow) * D + sg8;
    const __bf16* bP3 = B + (size_t)((tcol0 + 3) * BN + srow) * D + sg8;
    const int ldsOff = t * 8;

    auto stageA = [&](int buf, int slab, int k) {
        __builtin_amdgcn_global_load_lds(GLBP(aSrc + (size_t)slab * 64 * D + k),
                                         LDSP(&As[buf][slab * 4096 + ldsOff]), 16, 0, 0);
    };
    auto stageB = [&](int buf, int slab, const __bf16* bp, int k) {
        __builtin_amdgcn_global_load_lds(GLBP(bp + (size_t)slab * 64 * D + k),
                                         LDSP(&Bs[buf][slab * 4096 + ldsOff]), 16, 0, 0);
    };
    auto ldA = [&](int buf, int mh, int m, int g) {
        const int row = wm * 128 + mh * 64 + m * 16 + fr;
        return *reinterpret_cast<const bf16x8*>(&As[buf][row * 64 + g * 8]);
    };
    auto ldB = [&](int buf, int n, int g) {
        const int row = wn * 64 + n * 16 + fr;
        return *reinterpret_cast<const bf16x8*>(&Bs[buf][row * 64 + g * 8]);
    };

    f32x4 acc[8][4];
#pragma unroll
    for (int i = 0; i < 8; ++i)
#pragma unroll
        for (int n = 0; n < 4; ++n)
            acc[i][n] = (f32x4){0.f, 0.f, 0.f, 0.f};

    const int crow0 = brow + wm * 128;
    const int rr    = fq * 4;
    // fire-and-forget C store of acc for finished tile ip, then reset acc
    auto storeTile = [&](int ip) {
        const int ccol0 = (tcol0 + ip) * BN + wn * 64;
#pragma unroll
        for (int mh = 0; mh < 2; ++mh)
#pragma unroll
            for (int m = 0; m < 4; ++m)
#pragma unroll
                for (int r = 0; r < 4; ++r) {
                    const size_t rowoff = (size_t)(crow0 + mh * 64 + m * 16 + rr + r) * NC;
#pragma unroll
                    for (int n = 0; n < 4; ++n)
                        C[rowoff + ccol0 + n * 16 + fr] = acc[mh * 4 + m][n][r];
                }
#pragma unroll
        for (int i = 0; i < 8; ++i)
#pragma unroll
            for (int n = 0; n < 4; ++n)
                acc[i][n] = (f32x4){0.f, 0.f, 0.f, 0.f};
    };

    // ---- prologue: stage K-tile 0 (tile 0) into buf 0, drain once ----
    stageB(0, 0, bP0, 0); stageB(0, 1, bP0, 0); stageB(0, 2, bP0, 0); stageB(0, 3, bP0, 0);
    stageA(0, 0, 0); stageA(0, 2, 0); stageA(0, 1, 0); stageA(0, 3, 0);
    asm volatile("s_waitcnt vmcnt(0)" ::: "memory");
    __builtin_amdgcn_s_barrier();

    const int TOT = TPB * 16;   // D==1024 -> 16 K-tiles per output tile
    for (int g = 0; g < TOT; ++g) {
        const int p = g & 1, q = p ^ 1;
        const int g2  = (g + 1 < TOT) ? g + 1 : g;   // staged unit (dummy at end)
        const int kt2 = (g2 & 15) * BK;              // k offset of staged K-tile
        const int i2  = g2 >> 4;                     // tile index of staged K-tile
        const __bf16* bp2 = (i2 < 2) ? (i2 == 0 ? bP0 : bP1) : (i2 == 2 ? bP2 : bP3);
        const bool boundary = ((g & 15) == 0) && (g != 0);
        bf16x8 a[4], bfr[4];

        // ======== phase 1: kh=0, mh=0 | stage B0-3(g+1) ========
#pragma unroll
        for (int n = 0; n < 4; ++n) bfr[n] = ldB(p, n, g0);
#pragma unroll
        for (int m = 0; m < 4; ++m) a[m] = ldA(p, 0, m, g0);
        stageB(q, 0, bp2, kt2); stageB(q, 1, bp2, kt2);
        stageB(q, 2, bp2, kt2); stageB(q, 3, bp2, kt2);
        __builtin_amdgcn_s_barrier();
        if (boundary) {
            // retire A1,A3 of g BEFORE the stores enter the queue
            asm volatile("s_waitcnt vmcnt(4)" ::: "memory");
            storeTile((g >> 4) - 1);                 // 128 stores + acc reset
            __builtin_amdgcn_s_setprio(1);
#pragma unroll
            for (int m = 0; m < 4; ++m)
#pragma unroll
                for (int n = 0; n < 4; ++n)
                    acc[m][n] = __builtin_amdgcn_mfma_f32_16x16x32_bf16(a[m], bfr[n], acc[m][n], 0, 0, 0);
            __builtin_amdgcn_s_setprio(0);
        } else {
            __builtin_amdgcn_s_setprio(1);
#pragma unroll
            for (int m = 0; m < 4; ++m)
#pragma unroll
                for (int n = 0; n < 4; ++n)
                    acc[m][n] = __builtin_amdgcn_mfma_f32_16x16x32_bf16(a[m], bfr[n], acc[m][n], 0, 0, 0);
            __builtin_amdgcn_s_setprio(0);
            // retire A1,A3 of g (staged ph2 of g-1: 3-phase flight)
            asm volatile("s_waitcnt vmcnt(4)" ::: "memory");
        }
        __builtin_amdgcn_s_barrier();

        // ======== phase 2: kh=0, mh=1 (reuse bfr) | stage A(g+1) ========
#pragma unroll
        for (int m = 0; m < 4; ++m) a[m] = ldA(p, 1, m, g0);
        stageA(q, 0, kt2); stageA(q, 2, kt2); stageA(q, 1, kt2); stageA(q, 3, kt2);
        __builtin_amdgcn_s_barrier();
        __builtin_amdgcn_s_setprio(1);
#pragma unroll
        for (int m = 0; m < 4; ++m)
#pragma unroll
            for (int n = 0; n < 4; ++n)
                acc[4 + m][n] = __builtin_amdgcn_mfma_f32_16x16x32_bf16(a[m], bfr[n], acc[4 + m][n], 0, 0, 0);
        __builtin_amdgcn_s_setprio(0);
        __builtin_amdgcn_s_barrier();

        // ======== phase 3: kh=1, mh=0 ========
#pragma unroll
        for (int n = 0; n < 4; ++n) bfr[n] = ldB(p, n, g1);
#pragma unroll
        for (int m = 0; m < 4; ++m) a[m] = ldA(p, 0, m, g1);
        __builtin_amdgcn_s_barrier();
        __builtin_amdgcn_s_setprio(1);
#pragma unroll
        for (int m = 0; m < 4; ++m)
#pragma unroll
            for (int n = 0; n < 4; ++n)
                acc[m][n] = __builtin_amdgcn_mfma_f32_16x16x32_bf16(a[m], bfr[n], acc[m][n], 0, 0, 0);
        __builtin_amdgcn_s_setprio(0);
        __builtin_amdgcn_s_barrier();

        // ======== phase 4: kh=1, mh=1 ========
#pragma unroll
        for (int m = 0; m < 4; ++m) a[m] = ldA(p, 1, m, g1);
        __builtin_amdgcn_s_barrier();
        __builtin_amdgcn_s_setprio(1);
#pragma unroll
        for (int m = 0; m < 4; ++m)
#pragma unroll
            for (int n = 0; n < 4; ++n)
                acc[4 + m][n] = __builtin_amdgcn_mfma_f32_16x16x32_bf16(a[m], bfr[n], acc[4 + m][n], 0, 0, 0);
        __builtin_amdgcn_s_setprio(0);
        // retire B0-3,A0,A2 of g+1 (+ any boundary stores); keep A1,A3 of g+1
        asm volatile("s_waitcnt vmcnt(2)" ::: "memory");
        __builtin_amdgcn_s_barrier();
    }
    asm volatile("s_waitcnt vmcnt(0)" ::: "memory");  // drain dummies

    // ---- final epilogue: last tile ----
    {
        const int ccol0 = (tcol0 + TPB - 1) * BN + wn * 64;
#pragma unroll
        for (int mh = 0; mh < 2; ++mh)
#pragma unroll
            for (int m = 0; m < 4; ++m)
#pragma unroll
                for (int r = 0; r < 4; ++r) {
                    const size_t rowoff = (size_t)(crow0 + mh * 64 + m * 16 + rr + r) * NC;
#pragma unroll
                    for (int n = 0; n < 4; ++n)
                        C[rowoff + ccol0 + n * 16 + fr] = acc[mh * 4 + m][n][r];
                }
    }
}

// ---------------- fallback path (odd shapes / tiny ws) ----------------

__global__ __launch_bounds__(256) void rnorm_rows(const float* __restrict__ in,
                                                  float* __restrict__ rn, int D) {
    const int row = blockIdx.x;
    float ss = 0.f;
    for (int c = threadIdx.x; c < D; c += 256) {
        const float v = in[(size_t)row * D + c];
        ss += v * v;
    }
#pragma unroll
    for (int off = 32; off > 0; off >>= 1) ss += __shfl_down(ss, off, 64);
    __shared__ float red[4];
    if ((threadIdx.x & 63) == 0) red[threadIdx.x >> 6] = ss;
    __syncthreads();
    if (threadIdx.x == 0) {
        const float tot = red[0] + red[1] + red[2] + red[3];
        rn[row] = 1.0f / fmaxf(sqrtf(tot), EPS_CS);
    }
}

__global__ __launch_bounds__(256) void gemm_f32_fallback(const float* __restrict__ x1,
                                                         const float* __restrict__ x2,
                                                         const float* __restrict__ rn1,
                                                         const float* __restrict__ rn2,
                                                         float* __restrict__ C,
                                                         int NR, int NC, int D) {
    __shared__ float a[16][17], b[16][17];
    const int tx = threadIdx.x & 15, ty = threadIdx.x >> 4;
    const int row = blockIdx.y * 16 + ty;
    const int colb = blockIdx.x * 16;
    float acc = 0.f;
    for (int k0 = 0; k0 < D; k0 += 16) {
        a[ty][tx] = (row < NR && k0 + tx < D) ? x1[(size_t)row * D + k0 + tx] : 0.f;
        b[ty][tx] = (colb + ty < NC && k0 + tx < D) ? x2[(size_t)(colb + ty) * D + k0 + tx] : 0.f;
        __syncthreads();
#pragma unroll
        for (int k = 0; k < 16; ++k) acc += a[ty][k] * b[tx][k];
        __syncthreads();
    }
    if (row < NR && colb + tx < NC)
        C[(size_t)row * NC + colb + tx] = acc * rn1[row] * rn2[colb + tx];
}

// ---------------- launch ----------------

extern "C" void kernel_launch(void* const* d_in, const int* in_sizes, int n_in,
                              void* d_out, int out_size, void* d_ws, size_t ws_size,
                              hipStream_t stream) {
    const float* x1 = (const float*)d_in[0];
    const float* x2 = (const float*)d_in[1];
    float* C = (float*)d_out;

    const int D  = 1024;
    const int NR = in_sizes[0] / D;
    const int NC = in_sizes[1] / D;
    const int ntn   = NC / BN;
    const int tiles = (NR / BM) * ntn;

    const size_t need = ((size_t)NR + (size_t)NC) * (size_t)D * sizeof(__bf16);
    const bool fast = (in_sizes[0] % D == 0) && (in_sizes[1] % D == 0) &&
                      (NR % BM == 0) && (NC % BN == 0) &&
                      (ntn % TPB == 0) && ((tiles / TPB) % 8 == 0) &&
                      (ws_size >= need);

    if (fast) {
        __bf16* An = (__bf16*)d_ws;
        __bf16* Bn = An + (size_t)NR * D;
        nrm_bf16_1024<<<NR, 256, 0, stream>>>(x1, An);
        nrm_bf16_1024<<<NC, 256, 0, stream>>>(x2, Bn);
        gemm_nt_bf16_persist<<<tiles / TPB, 512, 0, stream>>>(An, Bn, C, NC, D);
    } else {
        float* rn1 = (float*)d_ws;
        float* rn2 = rn1 + NR;
        rnorm_rows<<<NR, 256, 0, stream>>>(x1, rn1, D);
        rnorm_rows<<<NC, 256, 0, stream>>>(x2, rn2, D);
        dim3 g((NC + 15) / 16, (NR + 15) / 16);
        gemm_f32_fallback<<<g, 256, 0, stream>>>(x1, x2, rn1, rn2, C, NR, NC, D);
    }
}

// Round 10
// 200.311 us; speedup vs baseline: 1.0773x; 1.0773x over previous
//
#include <hip/hip_runtime.h>
#include <hip/hip_bf16.h>
#include <math.h>

// PairwiseCosineSimilarity: C[n][m] = <x1[n],x2[m]> / (max(||x1||,eps)*max(||x2||,eps))
// Round 10: r5 skeleton (best, 178 us GEMM) + pinned LDS-drain placement:
//   - each phase: reads | stage | [lgkmcnt(4) partial drain] | BARRIER |
//     lgkmcnt(0) + sched_barrier(0)  <- drain INSIDE the MFMA region (m201/rule #18)
//     | setprio(1) MFMA setprio(0) | [vmcnt] | BARRIER
//   Theory: compiler was draining LDS reads BEFORE the barrier -> all-wave
//   ping-pong (LDS 2300cyc + MFMA 2480cyc serialize = observed 6675cyc/K-tile).
//   Post-barrier pinned drain lets the LDS backlog overlap the MFMA region.
// Everything else identical to r5: 256x256 tile, BK=64, 8 waves (2x4),
// double-buffered LDS, stages 4B@P1/4A@P2, vmcnt(4)@P1-end, vmcnt(2)@P4-end,
// zero-conflict XOR-swizzled LDS (pre-swizzled global source + swizzled read),
// XCD-aware bijective block swizzle. Norm dispatches merged into one.

typedef __bf16 bf16x8 __attribute__((ext_vector_type(8)));
typedef float  f32x4  __attribute__((ext_vector_type(4)));

#define LDSP(x) ((__attribute__((address_space(3))) void*)(x))
#define GLBP(x) ((const __attribute__((address_space(1))) void*)(x))

#define BM 256
#define BN 256
#define BK 64
#define EPS_CS 1e-8f

// ------------- normalize: one block per row of x1 or x2, D == 1024 -------------

__global__ __launch_bounds__(256) void nrm_bf16_1024_2(const float* __restrict__ in1,
                                                       const float* __restrict__ in2,
                                                       __bf16* __restrict__ out1,
                                                       __bf16* __restrict__ out2,
                                                       int NR) {
    const int r = blockIdx.x;
    const float* in = (r < NR) ? in1 : in2;
    __bf16* out = (r < NR) ? out1 : out2;
    const int row = (r < NR) ? r : r - NR;
    const int t = threadIdx.x;
    const float4 v = reinterpret_cast<const float4*>(in + (size_t)row * 1024)[t];
    float ss = v.x * v.x + v.y * v.y + v.z * v.z + v.w * v.w;
#pragma unroll
    for (int off = 32; off > 0; off >>= 1) ss += __shfl_down(ss, off, 64);
    __shared__ float red[4];
    const int lane = t & 63, wid = t >> 6;
    if (lane == 0) red[wid] = ss;
    __syncthreads();
    const float tot = red[0] + red[1] + red[2] + red[3];
    const float rn = 1.0f / fmaxf(sqrtf(tot), EPS_CS);
    ushort4 pk;
    pk.x = __builtin_bit_cast(unsigned short, (__bf16)(v.x * rn));
    pk.y = __builtin_bit_cast(unsigned short, (__bf16)(v.y * rn));
    pk.z = __builtin_bit_cast(unsigned short, (__bf16)(v.z * rn));
    pk.w = __builtin_bit_cast(unsigned short, (__bf16)(v.w * rn));
    reinterpret_cast<ushort4*>(out + (size_t)row * 1024)[t] = pk;
}

// ---------------- 256x256 pipelined MFMA GEMM:  C = A * B^T ----------------
// A[NR][D], B[NC][D] bf16 row-major; C[NR][NC] f32. NR,NC % 256 == 0, D % 64 == 0.
// Grid = (NR/256)*(NC/256), block = 512 (8 waves, 2x4). Per wave: 128x64 output,
// acc[8][4] f32x4. LDS: 2 x (A 256x64 + B 256x64) bf16 = 128 KB.

__global__ __launch_bounds__(512, 2) void gemm_nt_bf16_256(const __bf16* __restrict__ A,
                                                           const __bf16* __restrict__ B,
                                                           float* __restrict__ C,
                                                           int NC, int D) {
    __shared__ alignas(16) __bf16 As[2][BM * BK];   // 2 x 32 KB
    __shared__ alignas(16) __bf16 Bs[2][BN * BK];   // 2 x 32 KB

    const int t    = threadIdx.x;
    const int lane = t & 63;
    const int wid  = t >> 6;            // 0..7
    const int wm   = wid >> 2;          // 0..1  (128-row strip)
    const int wn   = wid & 3;           // 0..3  (64-col strip)
    const int fr   = lane & 15;         // fragment row/col
    const int fq   = lane >> 4;         // 0..3  (k sub-group)
    const int xk   = fr & 7;            // read XOR key == (row & 7)
    const int g0   = fq ^ xk;           // kh=0 physical 16B-group
    const int g1   = (4 + fq) ^ xk;     // kh=1 physical 16B-group

    // XCD-aware bijective block swizzle (grid % 8 == 0 on the fast path)
    const int nwg = gridDim.x;
    int swz = blockIdx.x;
    if ((nwg & 7) == 0) swz = (swz & 7) * (nwg >> 3) + (swz >> 3);
    const int ntn  = NC / BN;
    const int brow = (swz / ntn) * BM;
    const int bcol = (swz % ntn) * BN;

    // staging: thread t covers LDS elements [t*8, t*8+8) of a 64-row slab.
    // source k-group pre-swizzled: (t&7) ^ (row&7) (inverse of the read XOR).
    const int srow = t >> 3;                         // 0..63
    const int sg8  = ((t & 7) ^ (srow & 7)) << 3;
    const __bf16* aSrc = A + (size_t)(brow + srow) * D + sg8;
    const __bf16* bSrc = B + (size_t)(bcol + srow) * D + sg8;
    const int ldsOff = t * 8;

    auto stageA = [&](int buf, int slab, int k) {
        __builtin_amdgcn_global_load_lds(GLBP(aSrc + (size_t)slab * 64 * D + k),
                                         LDSP(&As[buf][slab * 4096 + ldsOff]), 16, 0, 0);
    };
    auto stageB = [&](int buf, int slab, int k) {
        __builtin_amdgcn_global_load_lds(GLBP(bSrc + (size_t)slab * 64 * D + k),
                                         LDSP(&Bs[buf][slab * 4096 + ldsOff]), 16, 0, 0);
    };
    auto ldA = [&](int buf, int mh, int m, int g) {
        const int row = wm * 128 + mh * 64 + m * 16 + fr;
        return *reinterpret_cast<const bf16x8*>(&As[buf][row * 64 + g * 8]);
    };
    auto ldB = [&](int buf, int n, int g) {
        const int row = wn * 64 + n * 16 + fr;
        return *reinterpret_cast<const bf16x8*>(&Bs[buf][row * 64 + g * 8]);
    };

    f32x4 acc[8][4];
#pragma unroll
    for (int i = 0; i < 8; ++i)
#pragma unroll
        for (int n = 0; n < 4; ++n)
            acc[i][n] = (f32x4){0.f, 0.f, 0.f, 0.f};

    // ---- prologue: stage K-tile 0 into buf 0, drain once ----
#pragma unroll
    for (int s = 0; s < 4; ++s) stageB(0, s, 0);
    stageA(0, 0, 0); stageA(0, 2, 0); stageA(0, 1, 0); stageA(0, 3, 0);
    asm volatile("s_waitcnt vmcnt(0)" ::: "memory");
    __builtin_amdgcn_s_barrier();

    const int NT = D / BK;
    int cur = 0;
    for (int kt = 0; kt < NT; ++kt) {
        const int nb = cur ^ 1;
        const int kn = (kt + 1 < NT ? kt + 1 : 0) * BK;  // last iter re-stages tile 0
                                                         // (dead slabs, never read)
        bf16x8 a[4], b[4];

        // ======== phase 1: kh=0, mh=0 | stage B0-3(t+1) ========
#pragma unroll
        for (int n = 0; n < 4; ++n) b[n] = ldB(cur, n, g0);
#pragma unroll
        for (int m = 0; m < 4; ++m) a[m] = ldA(cur, 0, m, g0);
        stageB(nb, 0, kn); stageB(nb, 1, kn); stageB(nb, 2, kn); stageB(nb, 3, kn);
        asm volatile("s_waitcnt lgkmcnt(4)" ::: "memory");   // partial pre-barrier drain
        __builtin_amdgcn_s_barrier();
        asm volatile("s_waitcnt lgkmcnt(0)" ::: "memory");   // drain INSIDE MFMA region
        __builtin_amdgcn_sched_barrier(0);                   // rule #18: pin MFMA after
        __builtin_amdgcn_s_setprio(1);
#pragma unroll
        for (int m = 0; m < 4; ++m)
#pragma unroll
            for (int n = 0; n < 4; ++n)
                acc[m][n] = __builtin_amdgcn_mfma_f32_16x16x32_bf16(a[m], b[n], acc[m][n], 0, 0, 0);
        __builtin_amdgcn_s_setprio(0);
        // retire A1,A3 of cur (staged P2 of kt-1: 3-phase flight)
        asm volatile("s_waitcnt vmcnt(4)" ::: "memory");
        __builtin_amdgcn_s_barrier();

        // ======== phase 2: kh=0, mh=1 (reuse b) | stage A(t+1) ========
#pragma unroll
        for (int m = 0; m < 4; ++m) a[m] = ldA(cur, 1, m, g0);
        stageA(nb, 0, kn); stageA(nb, 2, kn); stageA(nb, 1, kn); stageA(nb, 3, kn);
        __builtin_amdgcn_s_barrier();
        asm volatile("s_waitcnt lgkmcnt(0)" ::: "memory");
        __builtin_amdgcn_sched_barrier(0);
        __builtin_amdgcn_s_setprio(1);
#pragma unroll
        for (int m = 0; m < 4; ++m)
#pragma unroll
            for (int n = 0; n < 4; ++n)
                acc[4 + m][n] = __builtin_amdgcn_mfma_f32_16x16x32_bf16(a[m], b[n], acc[4 + m][n], 0, 0, 0);
        __builtin_amdgcn_s_setprio(0);
        __builtin_amdgcn_s_barrier();

        // ======== phase 3: kh=1, mh=0 ========
#pragma unroll
        for (int n = 0; n < 4; ++n) b[n] = ldB(cur, n, g1);
#pragma unroll
        for (int m = 0; m < 4; ++m) a[m] = ldA(cur, 0, m, g1);
        asm volatile("s_waitcnt lgkmcnt(4)" ::: "memory");   // partial pre-barrier drain
        __builtin_amdgcn_s_barrier();
        asm volatile("s_waitcnt lgkmcnt(0)" ::: "memory");
        __builtin_amdgcn_sched_barrier(0);
        __builtin_amdgcn_s_setprio(1);
#pragma unroll
        for (int m = 0; m < 4; ++m)
#pragma unroll
            for (int n = 0; n < 4; ++n)
                acc[m][n] = __builtin_amdgcn_mfma_f32_16x16x32_bf16(a[m], b[n], acc[m][n], 0, 0, 0);
        __builtin_amdgcn_s_setprio(0);
        __builtin_amdgcn_s_barrier();

        // ======== phase 4: kh=1, mh=1 ========
#pragma unroll
        for (int m = 0; m < 4; ++m) a[m] = ldA(cur, 1, m, g1);
        __builtin_amdgcn_s_barrier();
        asm volatile("s_waitcnt lgkmcnt(0)" ::: "memory");
        __builtin_amdgcn_sched_barrier(0);
        __builtin_amdgcn_s_setprio(1);
#pragma unroll
        for (int m = 0; m < 4; ++m)
#pragma unroll
            for (int n = 0; n < 4; ++n)
                acc[4 + m][n] = __builtin_amdgcn_mfma_f32_16x16x32_bf16(a[m], b[n], acc[4 + m][n], 0, 0, 0);
        __builtin_amdgcn_s_setprio(0);
        // retire B0-3,A0,A2 of t+1 (2-3 phase flight); keep A1,A3 of t+1
        asm volatile("s_waitcnt vmcnt(2)" ::: "memory");
        __builtin_amdgcn_s_barrier();

        cur = nb;
    }
    asm volatile("s_waitcnt vmcnt(0)" ::: "memory");  // drain dummy stages

    // ---- epilogue: D[row][col], col = lane&15, row = (lane>>4)*4 + reg ----
    const int crow0 = brow + wm * 128;
    const int ccol0 = bcol + wn * 64;
    const int rr    = fq * 4;
#pragma unroll
    for (int mh = 0; mh < 2; ++mh) {
#pragma unroll
        for (int m = 0; m < 4; ++m) {
#pragma unroll
            for (int r = 0; r < 4; ++r) {
                const size_t rowoff = (size_t)(crow0 + mh * 64 + m * 16 + rr + r) * NC;
#pragma unroll
                for (int n = 0; n < 4; ++n)
                    C[rowoff + ccol0 + n * 16 + fr] = acc[mh * 4 + m][n][r];
            }
        }
    }
}

// ---------------- fallback path (odd shapes / tiny ws) ----------------

__global__ __launch_bounds__(256) void rnorm_rows(const float* __restrict__ in,
                                                  float* __restrict__ rn, int D) {
    const int row = blockIdx.x;
    float ss = 0.f;
    for (int c = threadIdx.x; c < D; c += 256) {
        const float v = in[(size_t)row * D + c];
        ss += v * v;
    }
#pragma unroll
    for (int off = 32; off > 0; off >>= 1) ss += __shfl_down(ss, off, 64);
    __shared__ float red[4];
    if ((threadIdx.x & 63) == 0) red[threadIdx.x >> 6] = ss;
    __syncthreads();
    if (threadIdx.x == 0) {
        const float tot = red[0] + red[1] + red[2] + red[3];
        rn[row] = 1.0f / fmaxf(sqrtf(tot), EPS_CS);
    }
}

__global__ __launch_bounds__(256) void gemm_f32_fallback(const float* __restrict__ x1,
                                                         const float* __restrict__ x2,
                                                         const float* __restrict__ rn1,
                                                         const float* __restrict__ rn2,
                                                         float* __restrict__ C,
                                                         int NR, int NC, int D) {
    __shared__ float a[16][17], b[16][17];
    const int tx = threadIdx.x & 15, ty = threadIdx.x >> 4;
    const int row = blockIdx.y * 16 + ty;
    const int colb = blockIdx.x * 16;
    float acc = 0.f;
    for (int k0 = 0; k0 < D; k0 += 16) {
        a[ty][tx] = (row < NR && k0 + tx < D) ? x1[(size_t)row * D + k0 + tx] : 0.f;
        b[ty][tx] = (colb + ty < NC && k0 + tx < D) ? x2[(size_t)(colb + ty) * D + k0 + tx] : 0.f;
        __syncthreads();
#pragma unroll
        for (int k = 0; k < 16; ++k) acc += a[ty][k] * b[tx][k];
        __syncthreads();
    }
    if (row < NR && colb + tx < NC)
        C[(size_t)row * NC + colb + tx] = acc * rn1[row] * rn2[colb + tx];
}

// ---------------- launch ----------------

extern "C" void kernel_launch(void* const* d_in, const int* in_sizes, int n_in,
                              void* d_out, int out_size, void* d_ws, size_t ws_size,
                              hipStream_t stream) {
    const float* x1 = (const float*)d_in[0];
    const float* x2 = (const float*)d_in[1];
    float* C = (float*)d_out;

    const int D  = 1024;
    const int NR = in_sizes[0] / D;
    const int NC = in_sizes[1] / D;

    const size_t need = ((size_t)NR + (size_t)NC) * (size_t)D * sizeof(__bf16);
    const bool fast = (in_sizes[0] % D == 0) && (in_sizes[1] % D == 0) &&
                      (NR % BM == 0) && (NC % BN == 0) && (D / BK >= 2) &&
                      (ws_size >= need);

    if (fast) {
        __bf16* An = (__bf16*)d_ws;
        __bf16* Bn = An + (size_t)NR * D;
        nrm_bf16_1024_2<<<NR + NC, 256, 0, stream>>>(x1, x2, An, Bn, NR);
        const int grid = (NR / BM) * (NC / BN);
        gemm_nt_bf16_256<<<grid, 512, 0, stream>>>(An, Bn, C, NC, D);
    } else {
        float* rn1 = (float*)d_ws;
        float* rn2 = rn1 + NR;
        rnorm_rows<<<NR, 256, 0, stream>>>(x1, rn1, D);
        rnorm_rows<<<NC, 256, 0, stream>>>(x2, rn2, D);
        dim3 g((NC + 15) / 16, (NR + 15) / 16);
        gemm_f32_fallback<<<g, 256, 0, stream>>>(x1, x2, rn1, rn2, C, NR, NC, D);
    }
}

// Round 11
// 193.168 us; speedup vs baseline: 1.1172x; 1.0370x over previous
//
#include <hip/hip_runtime.h>
#include <hip/hip_bf16.h>
#include <math.h>

// PairwiseCosineSimilarity: C[n][m] = <x1[n],x2[m]> / (max(||x1||,eps)*max(||x2||,eps))
// Round 11: normalize rows -> bf16, then the m201 8-phase 256x256 MFMA GEMM,
// reconstructed from the template's numeric fingerprints:
//   - phase = C-QUADRANT (128x128) x full K=64; quadrant snake (0,0)(0,1)(1,1)(1,0)
//     so A-frags carry in regs (reads/phase: 12,4,8,4 -> 28/K-tile/wave).
//   - each LDS half-tile (128 rows of A or B, 2 gloads/thread) dies after ONE
//     phase -> stage exactly 1 half per phase, uniformly:
//       ph1: B-lo(odd)   ph2: A-lo(E+2)  ph3: B-hi(E+2)  ph4: A-hi(E+2)
//       ph5: B-lo(E+2)   ph6: A-lo(O+2)  ph7: B-hi(O+2)  ph8: A-hi(O+2)
//   - vmcnt(6) ONLY at ph4/ph8 (retires exactly the next tile's 4 halves;
//     3 halves always in flight; min flight 3 phases). Even tiles buf0, odd buf1.
//   - per phase: reads | stage | [lgkmcnt(8) if 12 reads] | barrier |
//     lgkmcnt(0)+sched_barrier(0) | setprio(1) 16 MFMA setprio(0) | [vmcnt(6)] | barrier
// Zero-conflict XOR-swizzled LDS (pre-swizzled global source + swizzled read),
// XCD-aware bijective block swizzle. Norm merged into one dispatch.

typedef __bf16 bf16x8 __attribute__((ext_vector_type(8)));
typedef float  f32x4  __attribute__((ext_vector_type(4)));

#define LDSP(x) ((__attribute__((address_space(3))) void*)(x))
#define GLBP(x) ((const __attribute__((address_space(1))) void*)(x))

#define BM 256
#define BN 256
#define BK 64
#define EPS_CS 1e-8f

// ------------- normalize: one block per row of x1 or x2, D == 1024 -------------

__global__ __launch_bounds__(256) void nrm_bf16_1024_2(const float* __restrict__ in1,
                                                       const float* __restrict__ in2,
                                                       __bf16* __restrict__ out1,
                                                       __bf16* __restrict__ out2,
                                                       int NR) {
    const int r = blockIdx.x;
    const float* in = (r < NR) ? in1 : in2;
    __bf16* out = (r < NR) ? out1 : out2;
    const int row = (r < NR) ? r : r - NR;
    const int t = threadIdx.x;
    const float4 v = reinterpret_cast<const float4*>(in + (size_t)row * 1024)[t];
    float ss = v.x * v.x + v.y * v.y + v.z * v.z + v.w * v.w;
#pragma unroll
    for (int off = 32; off > 0; off >>= 1) ss += __shfl_down(ss, off, 64);
    __shared__ float red[4];
    const int lane = t & 63, wid = t >> 6;
    if (lane == 0) red[wid] = ss;
    __syncthreads();
    const float tot = red[0] + red[1] + red[2] + red[3];
    const float rn = 1.0f / fmaxf(sqrtf(tot), EPS_CS);
    ushort4 pk;
    pk.x = __builtin_bit_cast(unsigned short, (__bf16)(v.x * rn));
    pk.y = __builtin_bit_cast(unsigned short, (__bf16)(v.y * rn));
    pk.z = __builtin_bit_cast(unsigned short, (__bf16)(v.z * rn));
    pk.w = __builtin_bit_cast(unsigned short, (__bf16)(v.w * rn));
    reinterpret_cast<ushort4*>(out + (size_t)row * 1024)[t] = pk;
}

// ---------------- 8-phase 256x256 MFMA GEMM:  C = A * B^T ----------------
// A[NR][D], B[NC][D] bf16 row-major; C[NR][NC] f32. NR,NC % 256 == 0,
// D % 128 == 0 (even # of K-tiles). Grid = (NR/256)*(NC/256), block = 512.
// 8 waves 2x4; per phase each wave computes its 64x32 slice of one 128x128
// C-quadrant: 4 mf x 2 nf x 2 ks = 16 MFMA. acc[2][2][4][2] f32x4 = 128 VGPR.

#define MFMA_QUAD(MH, NH)                                                          \
    _Pragma("unroll") for (int mf = 0; mf < 4; ++mf)                               \
    _Pragma("unroll") for (int nf = 0; nf < 2; ++nf)                               \
    _Pragma("unroll") for (int ks = 0; ks < 2; ++ks)                               \
        acc[MH][NH][mf][nf] = __builtin_amdgcn_mfma_f32_16x16x32_bf16(             \
            aF[mf][ks], bF[nf][ks], acc[MH][NH][mf][nf], 0, 0, 0)

#define OPEN_BAR()                                              \
    __builtin_amdgcn_s_barrier();                               \
    asm volatile("s_waitcnt lgkmcnt(0)" ::: "memory");          \
    __builtin_amdgcn_sched_barrier(0);                          \
    __builtin_amdgcn_s_setprio(1)

#define CLOSE_BAR()                                             \
    __builtin_amdgcn_s_setprio(0);                              \
    __builtin_amdgcn_s_barrier()

#define CLOSE_BAR_VM()                                          \
    __builtin_amdgcn_s_setprio(0);                              \
    asm volatile("s_waitcnt vmcnt(6)" ::: "memory");            \
    __builtin_amdgcn_s_barrier()

__global__ __launch_bounds__(512, 2) void gemm_nt_bf16_8ph(const __bf16* __restrict__ A,
                                                           const __bf16* __restrict__ B,
                                                           float* __restrict__ C,
                                                           int NC, int D) {
    __shared__ alignas(16) __bf16 As[2][BM * BK];   // 2 x 32 KB
    __shared__ alignas(16) __bf16 Bs[2][BN * BK];   // 2 x 32 KB

    const int t    = threadIdx.x;
    const int lane = t & 63;
    const int wid  = t >> 6;            // 0..7
    const int wm   = wid >> 2;          // 0..1
    const int wn   = wid & 3;           // 0..3
    const int fr   = lane & 15;         // fragment row/col
    const int fq   = lane >> 4;         // 0..3 (k sub-group)
    const int xk   = fr & 7;            // read XOR key == (row & 7)
    const int g0   = fq ^ xk;           // ks=0 physical 16B-group
    const int g1   = (4 + fq) ^ xk;     // ks=1 physical 16B-group

    // XCD-aware bijective block swizzle (grid % 8 == 0 on the fast path)
    const int nwg = gridDim.x;
    int swz = blockIdx.x;
    if ((nwg & 7) == 0) swz = (swz & 7) * (nwg >> 3) + (swz >> 3);
    const int ntn  = NC / BN;
    const int brow = (swz / ntn) * BM;
    const int bcol = (swz % ntn) * BN;

    // staging: thread t covers LDS elements [t*8, t*8+8) of a 64-row slab.
    // source k-group pre-swizzled: (t&7) ^ (row&7) (inverse of the read XOR).
    const int srow = t >> 3;                         // 0..63
    const int sg8  = ((t & 7) ^ (srow & 7)) << 3;
    const __bf16* aSrc = A + (size_t)(brow + srow) * D + sg8;
    const __bf16* bSrc = B + (size_t)(bcol + srow) * D + sg8;
    const int ldsOff = t * 8;

    auto stageA = [&](int buf, int slab, int k) {
        __builtin_amdgcn_global_load_lds(GLBP(aSrc + (size_t)slab * 64 * D + k),
                                         LDSP(&As[buf][slab * 4096 + ldsOff]), 16, 0, 0);
    };
    auto stageB = [&](int buf, int slab, int k) {
        __builtin_amdgcn_global_load_lds(GLBP(bSrc + (size_t)slab * 64 * D + k),
                                         LDSP(&Bs[buf][slab * 4096 + ldsOff]), 16, 0, 0);
    };
    auto ldA = [&](int buf, int mh, int mf, int g) {
        const int row = mh * 128 + wm * 64 + mf * 16 + fr;
        return *reinterpret_cast<const bf16x8*>(&As[buf][row * 64 + g * 8]);
    };
    auto ldB = [&](int buf, int nh, int nf, int g) {
        const int row = nh * 128 + wn * 32 + nf * 16 + fr;
        return *reinterpret_cast<const bf16x8*>(&Bs[buf][row * 64 + g * 8]);
    };

    f32x4 acc[2][2][4][2];   // [mh][nh][mf][nf]
#pragma unroll
    for (int i = 0; i < 2; ++i)
#pragma unroll
        for (int j = 0; j < 2; ++j)
#pragma unroll
            for (int mf = 0; mf < 4; ++mf)
#pragma unroll
                for (int nf = 0; nf < 2; ++nf)
                    acc[i][j][mf][nf] = (f32x4){0.f, 0.f, 0.f, 0.f};

    bf16x8 aF[4][2], bF[2][2];

    // ---- prologue: tile0 full (4 halves) + tile1 {A-lo, B-hi, A-hi} ----
    // (B-lo(1) is staged at iter0 PH1 -> steady state from the first phase.)
    stageA(0, 0, 0); stageA(0, 1, 0);        // A-lo(0)
    stageB(0, 0, 0); stageB(0, 1, 0);        // B-lo(0)
    stageB(0, 2, 0); stageB(0, 3, 0);        // B-hi(0)
    stageA(0, 2, 0); stageA(0, 3, 0);        // A-hi(0)
    stageA(1, 0, BK); stageA(1, 1, BK);      // A-lo(1)
    stageB(1, 2, BK); stageB(1, 3, BK);      // B-hi(1)
    stageA(1, 2, BK); stageA(1, 3, BK);      // A-hi(1)
    asm volatile("s_waitcnt vmcnt(6)" ::: "memory");   // retire tile0's 4 halves
    __builtin_amdgcn_s_barrier();

    const int NT = D / BK;   // even, >= 2
    const int NI = NT >> 1;
    for (int it = 0; it < NI; ++it) {
        const int kO  = (2 * it + 1) * BK;                       // odd tile (real)
        const int t2 = 2 * it + 2, t3 = 2 * it + 3;
        const int kE2 = (t2 < NT) ? t2 * BK : 0;                 // wrapped dummies
        const int kO2 = (t3 < NT) ? t3 * BK : 0;                 //   land in dead slabs

        // ==== PH1: even tile, quad(0,0) | reads A-lo+B-lo (12) | stage B-lo(odd)->buf1 ====
#pragma unroll
        for (int mf = 0; mf < 4; ++mf) { aF[mf][0] = ldA(0, 0, mf, g0); aF[mf][1] = ldA(0, 0, mf, g1); }
#pragma unroll
        for (int nf = 0; nf < 2; ++nf) { bF[nf][0] = ldB(0, 0, nf, g0); bF[nf][1] = ldB(0, 0, nf, g1); }
        stageB(1, 0, kO); stageB(1, 1, kO);
        asm volatile("s_waitcnt lgkmcnt(8)" ::: "memory");
        OPEN_BAR(); MFMA_QUAD(0, 0); CLOSE_BAR();

        // ==== PH2: quad(0,1) | reads B-hi (4, A kept) | stage A-lo(E+2)->buf0 ====
#pragma unroll
        for (int nf = 0; nf < 2; ++nf) { bF[nf][0] = ldB(0, 1, nf, g0); bF[nf][1] = ldB(0, 1, nf, g1); }
        stageA(0, 0, kE2); stageA(0, 1, kE2);
        OPEN_BAR(); MFMA_QUAD(0, 1); CLOSE_BAR();

        // ==== PH3: quad(1,1) | reads A-hi (8, B kept) | stage B-hi(E+2)->buf0 ====
#pragma unroll
        for (int mf = 0; mf < 4; ++mf) { aF[mf][0] = ldA(0, 1, mf, g0); aF[mf][1] = ldA(0, 1, mf, g1); }
        stageB(0, 2, kE2); stageB(0, 3, kE2);
        OPEN_BAR(); MFMA_QUAD(1, 1); CLOSE_BAR();

        // ==== PH4: quad(1,0) | reads B-lo again (4) | stage A-hi(E+2)->buf0 | vmcnt(6) ====
#pragma unroll
        for (int nf = 0; nf < 2; ++nf) { bF[nf][0] = ldB(0, 0, nf, g0); bF[nf][1] = ldB(0, 0, nf, g1); }
        stageA(0, 2, kE2); stageA(0, 3, kE2);
        OPEN_BAR(); MFMA_QUAD(1, 0); CLOSE_BAR_VM();   // retires odd tile's 4 halves

        // ==== PH5: odd tile, quad(0,0) | reads (12) | stage B-lo(E+2)->buf0 ====
#pragma unroll
        for (int mf = 0; mf < 4; ++mf) { aF[mf][0] = ldA(1, 0, mf, g0); aF[mf][1] = ldA(1, 0, mf, g1); }
#pragma unroll
        for (int nf = 0; nf < 2; ++nf) { bF[nf][0] = ldB(1, 0, nf, g0); bF[nf][1] = ldB(1, 0, nf, g1); }
        stageB(0, 0, kE2); stageB(0, 1, kE2);
        asm volatile("s_waitcnt lgkmcnt(8)" ::: "memory");
        OPEN_BAR(); MFMA_QUAD(0, 0); CLOSE_BAR();

        // ==== PH6: quad(0,1) | reads B-hi (4) | stage A-lo(O+2)->buf1 ====
#pragma unroll
        for (int nf = 0; nf < 2; ++nf) { bF[nf][0] = ldB(1, 1, nf, g0); bF[nf][1] = ldB(1, 1, nf, g1); }
        stageA(1, 0, kO2); stageA(1, 1, kO2);
        OPEN_BAR(); MFMA_QUAD(0, 1); CLOSE_BAR();

        // ==== PH7: quad(1,1) | reads A-hi (8) | stage B-hi(O+2)->buf1 ====
#pragma unroll
        for (int mf = 0; mf < 4; ++mf) { aF[mf][0] = ldA(1, 1, mf, g0); aF[mf][1] = ldA(1, 1, mf, g1); }
        stageB(1, 2, kO2); stageB(1, 3, kO2);
        OPEN_BAR(); MFMA_QUAD(1, 1); CLOSE_BAR();

        // ==== PH8: quad(1,0) | reads B-lo again (4) | stage A-hi(O+2)->buf1 | vmcnt(6) ====
#pragma unroll
        for (int nf = 0; nf < 2; ++nf) { bF[nf][0] = ldB(1, 0, nf, g0); bF[nf][1] = ldB(1, 0, nf, g1); }
        stageA(1, 2, kO2); stageA(1, 3, kO2);
        OPEN_BAR(); MFMA_QUAD(1, 0); CLOSE_BAR_VM();   // retires tile E+2's 4 halves
    }
    asm volatile("s_waitcnt vmcnt(0)" ::: "memory");   // drain tail dummies

    // ---- epilogue: row = mh*128+wm*64+mf*16+fq*4+r, col = nh*128+wn*32+nf*16+fr ----
#pragma unroll
    for (int mh = 0; mh < 2; ++mh)
#pragma unroll
        for (int nh = 0; nh < 2; ++nh)
#pragma unroll
            for (int mf = 0; mf < 4; ++mf)
#pragma unroll
                for (int r = 0; r < 4; ++r) {
                    const size_t rowoff =
                        (size_t)(brow + mh * 128 + wm * 64 + mf * 16 + fq * 4 + r) * NC;
#pragma unroll
                    for (int nf = 0; nf < 2; ++nf)
                        C[rowoff + bcol + nh * 128 + wn * 32 + nf * 16 + fr] =
                            acc[mh][nh][mf][nf][r];
                }
}

// ---------------- fallback path (odd shapes / tiny ws) ----------------

__global__ __launch_bounds__(256) void rnorm_rows(const float* __restrict__ in,
                                                  float* __restrict__ rn, int D) {
    const int row = blockIdx.x;
    float ss = 0.f;
    for (int c = threadIdx.x; c < D; c += 256) {
        const float v = in[(size_t)row * D + c];
        ss += v * v;
    }
#pragma unroll
    for (int off = 32; off > 0; off >>= 1) ss += __shfl_down(ss, off, 64);
    __shared__ float red[4];
    if ((threadIdx.x & 63) == 0) red[threadIdx.x >> 6] = ss;
    __syncthreads();
    if (threadIdx.x == 0) {
        const float tot = red[0] + red[1] + red[2] + red[3];
        rn[row] = 1.0f / fmaxf(sqrtf(tot), EPS_CS);
    }
}

__global__ __launch_bounds__(256) void gemm_f32_fallback(const float* __restrict__ x1,
                                                         const float* __restrict__ x2,
                                                         const float* __restrict__ rn1,
                                                         const float* __restrict__ rn2,
                                                         float* __restrict__ C,
                                                         int NR, int NC, int D) {
    __shared__ float a[16][17], b[16][17];
    const int tx = threadIdx.x & 15, ty = threadIdx.x >> 4;
    const int row = blockIdx.y * 16 + ty;
    const int colb = blockIdx.x * 16;
    float acc = 0.f;
    for (int k0 = 0; k0 < D; k0 += 16) {
        a[ty][tx] = (row < NR && k0 + tx < D) ? x1[(size_t)row * D + k0 + tx] : 0.f;
        b[ty][tx] = (colb + ty < NC && k0 + tx < D) ? x2[(size_t)(colb + ty) * D + k0 + tx] : 0.f;
        __syncthreads();
#pragma unroll
        for (int k = 0; k < 16; ++k) acc += a[ty][k] * b[tx][k];
        __syncthreads();
    }
    if (row < NR && colb + tx < NC)
        C[(size_t)row * NC + colb + tx] = acc * rn1[row] * rn2[colb + tx];
}

// ---------------- launch ----------------

extern "C" void kernel_launch(void* const* d_in, const int* in_sizes, int n_in,
                              void* d_out, int out_size, void* d_ws, size_t ws_size,
                              hipStream_t stream) {
    const float* x1 = (const float*)d_in[0];
    const float* x2 = (const float*)d_in[1];
    float* C = (float*)d_out;

    const int D  = 1024;
    const int NR = in_sizes[0] / D;
    const int NC = in_sizes[1] / D;

    const size_t need = ((size_t)NR + (size_t)NC) * (size_t)D * sizeof(__bf16);
    const bool fast = (in_sizes[0] % D == 0) && (in_sizes[1] % D == 0) &&
                      (NR % BM == 0) && (NC % BN == 0) &&
                      (D % (2 * BK) == 0) && (ws_size >= need);

    if (fast) {
        __bf16* An = (__bf16*)d_ws;
        __bf16* Bn = An + (size_t)NR * D;
        nrm_bf16_1024_2<<<NR + NC, 256, 0, stream>>>(x1, x2, An, Bn, NR);
        const int grid = (NR / BM) * (NC / BN);
        gemm_nt_bf16_8ph<<<grid, 512, 0, stream>>>(An, Bn, C, NC, D);
    } else {
        float* rn1 = (float*)d_ws;
        float* rn2 = rn1 + NR;
        rnorm_rows<<<NR, 256, 0, stream>>>(x1, rn1, D);
        rnorm_rows<<<NC, 256, 0, stream>>>(x2, rn2, D);
        dim3 g((NC + 15) / 16, (NR + 15) / 16);
        gemm_f32_fallback<<<g, 256, 0, stream>>>(x1, x2, rn1, rn2, C, NR, NC, D);
    }
}

// Round 12
// 184.668 us; speedup vs baseline: 1.1686x; 1.0460x over previous
//
#include <hip/hip_runtime.h>
#include <hip/hip_bf16.h>
#include <math.h>

// PairwiseCosineSimilarity: C[n][m] = <x1[n],x2[m]> / (max(||x1||,eps)*max(||x2||,eps))
// Round 12: r11 8-phase kernel UNCHANGED except block->tile mapping:
// 2-D SUPERTILE scheduling for L2 residency. Theory: K-loop is bound by
// staging-return BW (16 TB/s demand at full MFMA pace -> only L2 can feed it);
// old 1-D chunks gave each XCD 1x32 tile bands (16 MB B working set >> 4 MB L2)
// so B-staging missed to L3/HBM (FETCH 287 MB vs 33 MB inputs). New mapping:
// each XCD gets an 8-row x 4-col supertile of 256^2 tiles per generation
// (= its 32 concurrent blocks): per-K-tile unique slices = 384 KB (L2-fits),
// B-panels fixed per XCD across generations (fetched from HBM once).
//   xcd = b&7, idx = b>>3, gen = idx>>5, w = idx&31
//   tile-row = gen*8 + (w&7), tile-col = xcd*4 + (w>>3)     (bijective)
// Rest identical to r11: 8-phase quadrant-snake 256x256 GEMM, 1 half-tile
// staged per phase, vmcnt(6) at ph4/ph8 only, zero-conflict XOR-swizzled LDS,
// lgkmcnt(0)+sched_barrier inside MFMA region, setprio, merged norm pass.

typedef __bf16 bf16x8 __attribute__((ext_vector_type(8)));
typedef float  f32x4  __attribute__((ext_vector_type(4)));

#define LDSP(x) ((__attribute__((address_space(3))) void*)(x))
#define GLBP(x) ((const __attribute__((address_space(1))) void*)(x))

#define BM 256
#define BN 256
#define BK 64
#define EPS_CS 1e-8f

// ------------- normalize: one block per row of x1 or x2, D == 1024 -------------

__global__ __launch_bounds__(256) void nrm_bf16_1024_2(const float* __restrict__ in1,
                                                       const float* __restrict__ in2,
                                                       __bf16* __restrict__ out1,
                                                       __bf16* __restrict__ out2,
                                                       int NR) {
    const int r = blockIdx.x;
    const float* in = (r < NR) ? in1 : in2;
    __bf16* out = (r < NR) ? out1 : out2;
    const int row = (r < NR) ? r : r - NR;
    const int t = threadIdx.x;
    const float4 v = reinterpret_cast<const float4*>(in + (size_t)row * 1024)[t];
    float ss = v.x * v.x + v.y * v.y + v.z * v.z + v.w * v.w;
#pragma unroll
    for (int off = 32; off > 0; off >>= 1) ss += __shfl_down(ss, off, 64);
    __shared__ float red[4];
    const int lane = t & 63, wid = t >> 6;
    if (lane == 0) red[wid] = ss;
    __syncthreads();
    const float tot = red[0] + red[1] + red[2] + red[3];
    const float rn = 1.0f / fmaxf(sqrtf(tot), EPS_CS);
    ushort4 pk;
    pk.x = __builtin_bit_cast(unsigned short, (__bf16)(v.x * rn));
    pk.y = __builtin_bit_cast(unsigned short, (__bf16)(v.y * rn));
    pk.z = __builtin_bit_cast(unsigned short, (__bf16)(v.z * rn));
    pk.w = __builtin_bit_cast(unsigned short, (__bf16)(v.w * rn));
    reinterpret_cast<ushort4*>(out + (size_t)row * 1024)[t] = pk;
}

// ---------------- 8-phase 256x256 MFMA GEMM:  C = A * B^T ----------------

#define MFMA_QUAD(MH, NH)                                                          \
    _Pragma("unroll") for (int mf = 0; mf < 4; ++mf)                               \
    _Pragma("unroll") for (int nf = 0; nf < 2; ++nf)                               \
    _Pragma("unroll") for (int ks = 0; ks < 2; ++ks)                               \
        acc[MH][NH][mf][nf] = __builtin_amdgcn_mfma_f32_16x16x32_bf16(             \
            aF[mf][ks], bF[nf][ks], acc[MH][NH][mf][nf], 0, 0, 0)

#define OPEN_BAR()                                              \
    __builtin_amdgcn_s_barrier();                               \
    asm volatile("s_waitcnt lgkmcnt(0)" ::: "memory");          \
    __builtin_amdgcn_sched_barrier(0);                          \
    __builtin_amdgcn_s_setprio(1)

#define CLOSE_BAR()                                             \
    __builtin_amdgcn_s_setprio(0);                              \
    __builtin_amdgcn_s_barrier()

#define CLOSE_BAR_VM()                                          \
    __builtin_amdgcn_s_setprio(0);                              \
    asm volatile("s_waitcnt vmcnt(6)" ::: "memory");            \
    __builtin_amdgcn_s_barrier()

__global__ __launch_bounds__(512, 2) void gemm_nt_bf16_8ph(const __bf16* __restrict__ A,
                                                           const __bf16* __restrict__ B,
                                                           float* __restrict__ C,
                                                           int NC, int D) {
    __shared__ alignas(16) __bf16 As[2][BM * BK];   // 2 x 32 KB
    __shared__ alignas(16) __bf16 Bs[2][BN * BK];   // 2 x 32 KB

    const int t    = threadIdx.x;
    const int lane = t & 63;
    const int wid  = t >> 6;            // 0..7
    const int wm   = wid >> 2;          // 0..1
    const int wn   = wid & 3;           // 0..3
    const int fr   = lane & 15;         // fragment row/col
    const int fq   = lane >> 4;         // 0..3 (k sub-group)
    const int xk   = fr & 7;            // read XOR key == (row & 7)
    const int g0   = fq ^ xk;           // ks=0 physical 16B-group
    const int g1   = (4 + fq) ^ xk;     // ks=1 physical 16B-group

    // ---- block -> tile mapping: 2-D supertile (8 rows x 4 cols per XCD) ----
    const int nwg = gridDim.x;
    const int ntn = NC / BN;
    const int ntm = nwg / ntn;
    int brow_t, bcol_t;
    if (ntn == 32 && (ntm & 7) == 0 && (nwg & 7) == 0) {
        const int xcd = blockIdx.x & 7;
        const int idx = blockIdx.x >> 3;    // 0 .. nwg/8-1
        const int gen = idx >> 5;           // supertile-row (generation)
        const int w   = idx & 31;           // position within 8x4 supertile
        brow_t = gen * 8 + (w & 7);
        bcol_t = xcd * 4 + (w >> 3);
    } else if ((nwg & 7) == 0) {
        const int swz = (blockIdx.x & 7) * (nwg >> 3) + (blockIdx.x >> 3);
        brow_t = swz / ntn; bcol_t = swz % ntn;
    } else {
        brow_t = blockIdx.x / ntn; bcol_t = blockIdx.x % ntn;
    }
    const int brow = brow_t * BM;
    const int bcol = bcol_t * BN;

    // staging: thread t covers LDS elements [t*8, t*8+8) of a 64-row slab.
    // source k-group pre-swizzled: (t&7) ^ (row&7) (inverse of the read XOR).
    const int srow = t >> 3;                         // 0..63
    const int sg8  = ((t & 7) ^ (srow & 7)) << 3;
    const __bf16* aSrc = A + (size_t)(brow + srow) * D + sg8;
    const __bf16* bSrc = B + (size_t)(bcol + srow) * D + sg8;
    const int ldsOff = t * 8;

    auto stageA = [&](int buf, int slab, int k) {
        __builtin_amdgcn_global_load_lds(GLBP(aSrc + (size_t)slab * 64 * D + k),
                                         LDSP(&As[buf][slab * 4096 + ldsOff]), 16, 0, 0);
    };
    auto stageB = [&](int buf, int slab, int k) {
        __builtin_amdgcn_global_load_lds(GLBP(bSrc + (size_t)slab * 64 * D + k),
                                         LDSP(&Bs[buf][slab * 4096 + ldsOff]), 16, 0, 0);
    };
    auto ldA = [&](int buf, int mh, int mf, int g) {
        const int row = mh * 128 + wm * 64 + mf * 16 + fr;
        return *reinterpret_cast<const bf16x8*>(&As[buf][row * 64 + g * 8]);
    };
    auto ldB = [&](int buf, int nh, int nf, int g) {
        const int row = nh * 128 + wn * 32 + nf * 16 + fr;
        return *reinterpret_cast<const bf16x8*>(&Bs[buf][row * 64 + g * 8]);
    };

    f32x4 acc[2][2][4][2];   // [mh][nh][mf][nf]
#pragma unroll
    for (int i = 0; i < 2; ++i)
#pragma unroll
        for (int j = 0; j < 2; ++j)
#pragma unroll
            for (int mf = 0; mf < 4; ++mf)
#pragma unroll
                for (int nf = 0; nf < 2; ++nf)
                    acc[i][j][mf][nf] = (f32x4){0.f, 0.f, 0.f, 0.f};

    bf16x8 aF[4][2], bF[2][2];

    // ---- prologue: tile0 full (4 halves) + tile1 {A-lo, B-hi, A-hi} ----
    stageA(0, 0, 0); stageA(0, 1, 0);        // A-lo(0)
    stageB(0, 0, 0); stageB(0, 1, 0);        // B-lo(0)
    stageB(0, 2, 0); stageB(0, 3, 0);        // B-hi(0)
    stageA(0, 2, 0); stageA(0, 3, 0);        // A-hi(0)
    stageA(1, 0, BK); stageA(1, 1, BK);      // A-lo(1)
    stageB(1, 2, BK); stageB(1, 3, BK);      // B-hi(1)
    stageA(1, 2, BK); stageA(1, 3, BK);      // A-hi(1)
    asm volatile("s_waitcnt vmcnt(6)" ::: "memory");   // retire tile0's 4 halves
    __builtin_amdgcn_s_barrier();

    const int NT = D / BK;   // even, >= 2
    const int NI = NT >> 1;
    for (int it = 0; it < NI; ++it) {
        const int kO  = (2 * it + 1) * BK;                       // odd tile (real)
        const int t2 = 2 * it + 2, t3 = 2 * it + 3;
        const int kE2 = (t2 < NT) ? t2 * BK : 0;                 // wrapped dummies
        const int kO2 = (t3 < NT) ? t3 * BK : 0;                 //   land in dead slabs

        // ==== PH1: even tile, quad(0,0) | reads A-lo+B-lo (12) | stage B-lo(odd)->buf1 ====
#pragma unroll
        for (int mf = 0; mf < 4; ++mf) { aF[mf][0] = ldA(0, 0, mf, g0); aF[mf][1] = ldA(0, 0, mf, g1); }
#pragma unroll
        for (int nf = 0; nf < 2; ++nf) { bF[nf][0] = ldB(0, 0, nf, g0); bF[nf][1] = ldB(0, 0, nf, g1); }
        stageB(1, 0, kO); stageB(1, 1, kO);
        asm volatile("s_waitcnt lgkmcnt(8)" ::: "memory");
        OPEN_BAR(); MFMA_QUAD(0, 0); CLOSE_BAR();

        // ==== PH2: quad(0,1) | reads B-hi (4, A kept) | stage A-lo(E+2)->buf0 ====
#pragma unroll
        for (int nf = 0; nf < 2; ++nf) { bF[nf][0] = ldB(0, 1, nf, g0); bF[nf][1] = ldB(0, 1, nf, g1); }
        stageA(0, 0, kE2); stageA(0, 1, kE2);
        OPEN_BAR(); MFMA_QUAD(0, 1); CLOSE_BAR();

        // ==== PH3: quad(1,1) | reads A-hi (8, B kept) | stage B-hi(E+2)->buf0 ====
#pragma unroll
        for (int mf = 0; mf < 4; ++mf) { aF[mf][0] = ldA(0, 1, mf, g0); aF[mf][1] = ldA(0, 1, mf, g1); }
        stageB(0, 2, kE2); stageB(0, 3, kE2);
        OPEN_BAR(); MFMA_QUAD(1, 1); CLOSE_BAR();

        // ==== PH4: quad(1,0) | reads B-lo again (4) | stage A-hi(E+2)->buf0 | vmcnt(6) ====
#pragma unroll
        for (int nf = 0; nf < 2; ++nf) { bF[nf][0] = ldB(0, 0, nf, g0); bF[nf][1] = ldB(0, 0, nf, g1); }
        stageA(0, 2, kE2); stageA(0, 3, kE2);
        OPEN_BAR(); MFMA_QUAD(1, 0); CLOSE_BAR_VM();   // retires odd tile's 4 halves

        // ==== PH5: odd tile, quad(0,0) | reads (12) | stage B-lo(E+2)->buf0 ====
#pragma unroll
        for (int mf = 0; mf < 4; ++mf) { aF[mf][0] = ldA(1, 0, mf, g0); aF[mf][1] = ldA(1, 0, mf, g1); }
#pragma unroll
        for (int nf = 0; nf < 2; ++nf) { bF[nf][0] = ldB(1, 0, nf, g0); bF[nf][1] = ldB(1, 0, nf, g1); }
        stageB(0, 0, kE2); stageB(0, 1, kE2);
        asm volatile("s_waitcnt lgkmcnt(8)" ::: "memory");
        OPEN_BAR(); MFMA_QUAD(0, 0); CLOSE_BAR();

        // ==== PH6: quad(0,1) | reads B-hi (4) | stage A-lo(O+2)->buf1 ====
#pragma unroll
        for (int nf = 0; nf < 2; ++nf) { bF[nf][0] = ldB(1, 1, nf, g0); bF[nf][1] = ldB(1, 1, nf, g1); }
        stageA(1, 0, kO2); stageA(1, 1, kO2);
        OPEN_BAR(); MFMA_QUAD(0, 1); CLOSE_BAR();

        // ==== PH7: quad(1,1) | reads A-hi (8) | stage B-hi(O+2)->buf1 ====
#pragma unroll
        for (int mf = 0; mf < 4; ++mf) { aF[mf][0] = ldA(1, 1, mf, g0); aF[mf][1] = ldA(1, 1, mf, g1); }
        stageB(1, 2, kO2); stageB(1, 3, kO2);
        OPEN_BAR(); MFMA_QUAD(1, 1); CLOSE_BAR();

        // ==== PH8: quad(1,0) | reads B-lo again (4) | stage A-hi(O+2)->buf1 | vmcnt(6) ====
#pragma unroll
        for (int nf = 0; nf < 2; ++nf) { bF[nf][0] = ldB(1, 0, nf, g0); bF[nf][1] = ldB(1, 0, nf, g1); }
        stageA(1, 2, kO2); stageA(1, 3, kO2);
        OPEN_BAR(); MFMA_QUAD(1, 0); CLOSE_BAR_VM();   // retires tile E+2's 4 halves
    }
    asm volatile("s_waitcnt vmcnt(0)" ::: "memory");   // drain tail dummies

    // ---- epilogue: row = mh*128+wm*64+mf*16+fq*4+r, col = nh*128+wn*32+nf*16+fr ----
#pragma unroll
    for (int mh = 0; mh < 2; ++mh)
#pragma unroll
        for (int nh = 0; nh < 2; ++nh)
#pragma unroll
            for (int mf = 0; mf < 4; ++mf)
#pragma unroll
                for (int r = 0; r < 4; ++r) {
                    const size_t rowoff =
                        (size_t)(brow + mh * 128 + wm * 64 + mf * 16 + fq * 4 + r) * NC;
#pragma unroll
                    for (int nf = 0; nf < 2; ++nf)
                        C[rowoff + bcol + nh * 128 + wn * 32 + nf * 16 + fr] =
                            acc[mh][nh][mf][nf][r];
                }
}

// ---------------- fallback path (odd shapes / tiny ws) ----------------

__global__ __launch_bounds__(256) void rnorm_rows(const float* __restrict__ in,
                                                  float* __restrict__ rn, int D) {
    const int row = blockIdx.x;
    float ss = 0.f;
    for (int c = threadIdx.x; c < D; c += 256) {
        const float v = in[(size_t)row * D + c];
        ss += v * v;
    }
#pragma unroll
    for (int off = 32; off > 0; off >>= 1) ss += __shfl_down(ss, off, 64);
    __shared__ float red[4];
    if ((threadIdx.x & 63) == 0) red[threadIdx.x >> 6] = ss;
    __syncthreads();
    if (threadIdx.x == 0) {
        const float tot = red[0] + red[1] + red[2] + red[3];
        rn[row] = 1.0f / fmaxf(sqrtf(tot), EPS_CS);
    }
}

__global__ __launch_bounds__(256) void gemm_f32_fallback(const float* __restrict__ x1,
                                                         const float* __restrict__ x2,
                                                         const float* __restrict__ rn1,
                                                         const float* __restrict__ rn2,
                                                         float* __restrict__ C,
                                                         int NR, int NC, int D) {
    __shared__ float a[16][17], b[16][17];
    const int tx = threadIdx.x & 15, ty = threadIdx.x >> 4;
    const int row = blockIdx.y * 16 + ty;
    const int colb = blockIdx.x * 16;
    float acc = 0.f;
    for (int k0 = 0; k0 < D; k0 += 16) {
        a[ty][tx] = (row < NR && k0 + tx < D) ? x1[(size_t)row * D + k0 + tx] : 0.f;
        b[ty][tx] = (colb + ty < NC && k0 + tx < D) ? x2[(size_t)(colb + ty) * D + k0 + tx] : 0.f;
        __syncthreads();
#pragma unroll
        for (int k = 0; k < 16; ++k) acc += a[ty][k] * b[tx][k];
        __syncthreads();
    }
    if (row < NR && colb + tx < NC)
        C[(size_t)row * NC + colb + tx] = acc * rn1[row] * rn2[colb + tx];
}

// ---------------- launch ----------------

extern "C" void kernel_launch(void* const* d_in, const int* in_sizes, int n_in,
                              void* d_out, int out_size, void* d_ws, size_t ws_size,
                              hipStream_t stream) {
    const float* x1 = (const float*)d_in[0];
    const float* x2 = (const float*)d_in[1];
    float* C = (float*)d_out;

    const int D  = 1024;
    const int NR = in_sizes[0] / D;
    const int NC = in_sizes[1] / D;

    const size_t need = ((size_t)NR + (size_t)NC) * (size_t)D * sizeof(__bf16);
    const bool fast = (in_sizes[0] % D == 0) && (in_sizes[1] % D == 0) &&
                      (NR % BM == 0) && (NC % BN == 0) &&
                      (D % (2 * BK) == 0) && (ws_size >= need);

    if (fast) {
        __bf16* An = (__bf16*)d_ws;
        __bf16* Bn = An + (size_t)NR * D;
        nrm_bf16_1024_2<<<NR + NC, 256, 0, stream>>>(x1, x2, An, Bn, NR);
        const int grid = (NR / BM) * (NC / BN);
        gemm_nt_bf16_8ph<<<grid, 512, 0, stream>>>(An, Bn, C, NC, D);
    } else {
        float* rn1 = (float*)d_ws;
        float* rn2 = rn1 + NR;
        rnorm_rows<<<NR, 256, 0, stream>>>(x1, rn1, D);
        rnorm_rows<<<NC, 256, 0, stream>>>(x2, rn2, D);
        dim3 g((NC + 15) / 16, (NR + 15) / 16);
        gemm_f32_fallback<<<g, 256, 0, stream>>>(x1, x2, rn1, rn2, C, NR, NC, D);
    }
}

// Round 13
// 166.605 us; speedup vs baseline: 1.2953x; 1.1084x over previous
//
#include <hip/hip_runtime.h>
#include <hip/hip_bf16.h>
#include <math.h>

// PairwiseCosineSimilarity: C[n][m] = <x1[n],x2[m]> / (max(||x1||,eps)*max(||x2||,eps))
// Round 13: normalize rows -> bf16, then the m97-anchor GEMM:
//   128x128 tile, BK=64, 4 waves (2x2), SINGLE-buffered 32 KB LDS,
//   simple 2-sync loop (stage -> sync -> compute -> sync), compiler-scheduled
//   waits. The engine is INTER-BLOCK overlap: __launch_bounds__(256,4) +
//   32 KB LDS + ~120 VGPR -> 4 blocks/CU co-resident; one block's staging
//   drain overlaps another's MFMA (m97/m114 mechanism, 898 TF @8k in m192).
//   + 2-D supertile block mapping (proved -2.7x FETCH in round 12) so staging
//   is L2-fed: per XCD-generation a 16-row x 8-col tile supertile; B-strip
//   (8 tile-cols = 2 MB) fixed per XCD across generations.
// Zero-conflict XOR-swizzled LDS (pre-swizzled global source + swizzled read),
// merged norm pass. All fragment layouts identical to the r4/r12 kernels
// (verified passing).

typedef __bf16 bf16x8 __attribute__((ext_vector_type(8)));
typedef float  f32x4  __attribute__((ext_vector_type(4)));

#define LDSP(x) ((__attribute__((address_space(3))) void*)(x))
#define GLBP(x) ((const __attribute__((address_space(1))) void*)(x))

#define BM 128
#define BN 128
#define BK 64
#define EPS_CS 1e-8f

// ------------- normalize: one block per row of x1 or x2, D == 1024 -------------

__global__ __launch_bounds__(256) void nrm_bf16_1024_2(const float* __restrict__ in1,
                                                       const float* __restrict__ in2,
                                                       __bf16* __restrict__ out1,
                                                       __bf16* __restrict__ out2,
                                                       int NR) {
    const int r = blockIdx.x;
    const float* in = (r < NR) ? in1 : in2;
    __bf16* out = (r < NR) ? out1 : out2;
    const int row = (r < NR) ? r : r - NR;
    const int t = threadIdx.x;
    const float4 v = reinterpret_cast<const float4*>(in + (size_t)row * 1024)[t];
    float ss = v.x * v.x + v.y * v.y + v.z * v.z + v.w * v.w;
#pragma unroll
    for (int off = 32; off > 0; off >>= 1) ss += __shfl_down(ss, off, 64);
    __shared__ float red[4];
    const int lane = t & 63, wid = t >> 6;
    if (lane == 0) red[wid] = ss;
    __syncthreads();
    const float tot = red[0] + red[1] + red[2] + red[3];
    const float rn = 1.0f / fmaxf(sqrtf(tot), EPS_CS);
    ushort4 pk;
    pk.x = __builtin_bit_cast(unsigned short, (__bf16)(v.x * rn));
    pk.y = __builtin_bit_cast(unsigned short, (__bf16)(v.y * rn));
    pk.z = __builtin_bit_cast(unsigned short, (__bf16)(v.z * rn));
    pk.w = __builtin_bit_cast(unsigned short, (__bf16)(v.w * rn));
    reinterpret_cast<ushort4*>(out + (size_t)row * 1024)[t] = pk;
}

// ---------------- 128x128 m97-structure MFMA GEMM:  C = A * B^T ----------------
// A[NR][D], B[NC][D] bf16 row-major; C[NR][NC] f32. NR,NC % 128 == 0, D % 64 == 0.
// Grid = (NR/128)*(NC/128), block = 256 (4 waves, 2x2). Per wave: 64x64 output,
// acc[4][4] f32x4 = 64 VGPR. LDS: A[128x64] + B[128x64] bf16 = 32 KB, single-buf.
// __launch_bounds__(256,4): 4 waves/EU -> VGPR<=128 -> 4 blocks/CU co-resident.

__global__ __launch_bounds__(256, 4) void gemm_nt_bf16_128(const __bf16* __restrict__ A,
                                                           const __bf16* __restrict__ B,
                                                           float* __restrict__ C,
                                                           int NC, int D) {
    __shared__ alignas(16) __bf16 As[BM * BK];   // 16 KB
    __shared__ alignas(16) __bf16 Bs[BN * BK];   // 16 KB

    const int t    = threadIdx.x;
    const int lane = t & 63;
    const int wid  = t >> 6;            // 0..3
    const int wr   = wid >> 1;          // wave row 0..1 (64-row strips)
    const int wc   = wid & 1;           // wave col 0..1 (64-col strips)
    const int fr   = lane & 15;         // fragment row/col within 16
    const int fq   = lane >> 4;         // 0..3 (k sub-group)
    const int xk   = fr & 7;            // read XOR key == (row & 7)
    const int g0   = fq ^ xk;           // kh=0 physical 16B-group
    const int g1   = (4 + fq) ^ xk;     // kh=1 physical 16B-group

    // ---- block -> tile mapping: 2-D supertile (16 rows x 8 cols per XCD) ----
    const int nwg = gridDim.x;
    const int ntn = NC / BN;
    const int ntm = nwg / ntn;
    int tr, tc;
    if (ntn == 64 && (ntm & 15) == 0) {
        const int xcd = blockIdx.x & 7;
        const int i   = blockIdx.x >> 3;    // 0 .. nwg/8-1
        const int gen = i >> 7;             // supertile generation (16 tile-rows each)
        const int w   = i & 127;            // position within 16x8 supertile
        tr = gen * 16 + (w & 15);
        tc = xcd * 8 + (w >> 4);
    } else if ((nwg & 7) == 0) {
        const int swz = (blockIdx.x & 7) * (nwg >> 3) + (blockIdx.x >> 3);
        tr = swz / ntn; tc = swz % ntn;
    } else {
        tr = blockIdx.x / ntn; tc = blockIdx.x % ntn;
    }
    const int brow = tr * BM;
    const int bcol = tc * BN;

    // staging: thread t covers LDS elements [s*8, s*8+8) of slab s = i*256+t.
    // row = i*32 + (t>>3), lds k-group = t&7; global k-group pre-swizzled:
    // (t&7) ^ (row&7)  (inverse of the read XOR).
    const int srow = t >> 3;                         // 0..31
    const int sg8  = ((t & 7) ^ (srow & 7)) << 3;
    const __bf16* aSrc = A + (size_t)(brow + srow) * D + sg8;
    const __bf16* bSrc = B + (size_t)(bcol + srow) * D + sg8;

    f32x4 acc[4][4];
#pragma unroll
    for (int m = 0; m < 4; ++m)
#pragma unroll
        for (int n = 0; n < 4; ++n)
            acc[m][n] = (f32x4){0.f, 0.f, 0.f, 0.f};

    const int NT = D / BK;
    for (int kt = 0; kt < NT; ++kt) {
        const int k0 = kt * BK;
        // ---- stage A,B tiles (128x64 bf16 each) via global_load_lds x16B ----
#pragma unroll
        for (int i = 0; i < 4; ++i)
            __builtin_amdgcn_global_load_lds(
                GLBP(aSrc + (size_t)(i * 32) * D + k0),
                LDSP(&As[(i * 256 + t) * 8]), 16, 0, 0);
#pragma unroll
        for (int i = 0; i < 4; ++i)
            __builtin_amdgcn_global_load_lds(
                GLBP(bSrc + (size_t)(i * 32) * D + k0),
                LDSP(&Bs[(i * 256 + t) * 8]), 16, 0, 0);
        __syncthreads();   // compiler drains vmcnt before s_barrier

        // ---- compute: 2 k-slices of 32, 16 MFMA each ----
#pragma unroll
        for (int kk = 0; kk < 2; ++kk) {
            const int g = kk ? g1 : g0;
            bf16x8 af[4], bf[4];
#pragma unroll
            for (int m = 0; m < 4; ++m)
                af[m] = *reinterpret_cast<const bf16x8*>(&As[(wr * 64 + m * 16 + fr) * BK + g * 8]);
#pragma unroll
            for (int n = 0; n < 4; ++n)
                bf[n] = *reinterpret_cast<const bf16x8*>(&Bs[(wc * 64 + n * 16 + fr) * BK + g * 8]);
#pragma unroll
            for (int m = 0; m < 4; ++m)
#pragma unroll
                for (int n = 0; n < 4; ++n)
                    acc[m][n] = __builtin_amdgcn_mfma_f32_16x16x32_bf16(af[m], bf[n], acc[m][n], 0, 0, 0);
        }
        __syncthreads();   // protect LDS from next iteration's staging
    }

    // ---- epilogue: D[row][col], col = lane&15, row = (lane>>4)*4 + reg ----
    const int crow0 = brow + wr * 64;
    const int ccol0 = bcol + wc * 64;
    const int rr    = fq * 4;
#pragma unroll
    for (int m = 0; m < 4; ++m) {
#pragma unroll
        for (int r = 0; r < 4; ++r) {
            const size_t rowoff = (size_t)(crow0 + m * 16 + rr + r) * NC;
#pragma unroll
            for (int n = 0; n < 4; ++n)
                C[rowoff + ccol0 + n * 16 + fr] = acc[m][n][r];
        }
    }
}

// ---------------- fallback path (odd shapes / tiny ws) ----------------

__global__ __launch_bounds__(256) void rnorm_rows(const float* __restrict__ in,
                                                  float* __restrict__ rn, int D) {
    const int row = blockIdx.x;
    float ss = 0.f;
    for (int c = threadIdx.x; c < D; c += 256) {
        const float v = in[(size_t)row * D + c];
        ss += v * v;
    }
#pragma unroll
    for (int off = 32; off > 0; off >>= 1) ss += __shfl_down(ss, off, 64);
    __shared__ float red[4];
    if ((threadIdx.x & 63) == 0) red[threadIdx.x >> 6] = ss;
    __syncthreads();
    if (threadIdx.x == 0) {
        const float tot = red[0] + red[1] + red[2] + red[3];
        rn[row] = 1.0f / fmaxf(sqrtf(tot), EPS_CS);
    }
}

__global__ __launch_bounds__(256) void gemm_f32_fallback(const float* __restrict__ x1,
                                                         const float* __restrict__ x2,
                                                         const float* __restrict__ rn1,
                                                         const float* __restrict__ rn2,
                                                         float* __restrict__ C,
                                                         int NR, int NC, int D) {
    __shared__ float a[16][17], b[16][17];
    const int tx = threadIdx.x & 15, ty = threadIdx.x >> 4;
    const int row = blockIdx.y * 16 + ty;
    const int colb = blockIdx.x * 16;
    float acc = 0.f;
    for (int k0 = 0; k0 < D; k0 += 16) {
        a[ty][tx] = (row < NR && k0 + tx < D) ? x1[(size_t)row * D + k0 + tx] : 0.f;
        b[ty][tx] = (colb + ty < NC && k0 + tx < D) ? x2[(size_t)(colb + ty) * D + k0 + tx] : 0.f;
        __syncthreads();
#pragma unroll
        for (int k = 0; k < 16; ++k) acc += a[ty][k] * b[tx][k];
        __syncthreads();
    }
    if (row < NR && colb + tx < NC)
        C[(size_t)row * NC + colb + tx] = acc * rn1[row] * rn2[colb + tx];
}

// ---------------- launch ----------------

extern "C" void kernel_launch(void* const* d_in, const int* in_sizes, int n_in,
                              void* d_out, int out_size, void* d_ws, size_t ws_size,
                              hipStream_t stream) {
    const float* x1 = (const float*)d_in[0];
    const float* x2 = (const float*)d_in[1];
    float* C = (float*)d_out;

    const int D  = 1024;
    const int NR = in_sizes[0] / D;
    const int NC = in_sizes[1] / D;

    const size_t need = ((size_t)NR + (size_t)NC) * (size_t)D * sizeof(__bf16);
    const bool fast = (in_sizes[0] % D == 0) && (in_sizes[1] % D == 0) &&
                      (NR % BM == 0) && (NC % BN == 0) && (D % BK == 0) &&
                      (ws_size >= need);

    if (fast) {
        __bf16* An = (__bf16*)d_ws;
        __bf16* Bn = An + (size_t)NR * D;
        nrm_bf16_1024_2<<<NR + NC, 256, 0, stream>>>(x1, x2, An, Bn, NR);
        const int grid = (NR / BM) * (NC / BN);
        gemm_nt_bf16_128<<<grid, 256, 0, stream>>>(An, Bn, C, NC, D);
    } else {
        float* rn1 = (float*)d_ws;
        float* rn2 = rn1 + NR;
        rnorm_rows<<<NR, 256, 0, stream>>>(x1, rn1, D);
        rnorm_rows<<<NC, 256, 0, stream>>>(x2, rn2, D);
        dim3 g((NC + 15) / 16, (NR + 15) / 16);
        gemm_f32_fallback<<<g, 256, 0, stream>>>(x1, x2, rn1, rn2, C, NR, NC, D);
    }
}